// Round 1
// baseline (917.236 us; speedup 1.0000x reference)
//
#include <hip/hip_runtime.h>
#include <math.h>

// ---------------------------------------------------------------------------
// Sinkhorn ETP (FASTopic) on MI355X.
// n=256 topics, m=32768 words, D=384.
//
// State reduction (derived from the reference, see session notes):
//   log_K0[i,j] = G[i,j] + su0[i] + sv0[j],  G = 40 * x@y^T
//   su[i] = (su0+cum_u+log_u)[i],  W[j] = (sv0+cum_v+log_v)[j]
//   Per iteration:  L1[j] = lse_i(G+su);  W[j] = log_b - L1[j]
//                   L2[i] = lse_j(G+W);   su'[i] = log_a - L2[i]
//   (identical for keep and absorb branches; absorb only adds the column
//    marginal error check col[j] = exp(lse_i(G+su') + W[j]), row err == 0.)
//   Final: transp[i,j] = exp(G+su[i]+W[j]); M = nx[i]+ny[j]-0.05*G;
//          loss = sum(transp*M)
// ---------------------------------------------------------------------------

#define N_TOPIC 256
#define N_WORD  32768

static __device__ __forceinline__ float lse_merge_m(float m, float pm) { return fmaxf(m, pm); }

static constexpr float LOG_A = -5.545177444479562f;    // log(1/256 + 1e-30)
static constexpr float LOG_B = -10.397207708399179f;   // log(1/32768 + 1e-30)
static constexpr float BVAL  = 3.0517578125e-05f;      // 1/32768

// ---------------------------------------------------------------- init ------
__global__ __launch_bounds__(256) void init_k(
    const float* __restrict__ x, const float* __restrict__ y,
    float* __restrict__ nx, float* __restrict__ ny, float* __restrict__ su,
    unsigned* __restrict__ colerr, int* __restrict__ active, float* __restrict__ out)
{
    const int b = blockIdx.x, t = threadIdx.x;
    const int w = t >> 6, l = t & 63;
    if (b < 8192) {                       // ||y_j||^2, 4 rows/block (wave per row)
        const int r = (b << 2) + w;
        const float4* y4 = (const float4*)y;
        float4 v = y4[r * 96 + l];
        float s = v.x * v.x + v.y * v.y + v.z * v.z + v.w * v.w;
        if (l < 32) {
            float4 u = y4[r * 96 + 64 + l];
            s += u.x * u.x + u.y * u.y + u.z * u.z + u.w * u.w;
        }
        for (int off = 32; off; off >>= 1) s += __shfl_down(s, off);
        if (l == 0) ny[r] = s;
    } else if (b < 8256) {                // ||x_i||^2 and su0 = -20*nx
        const int r = ((b - 8192) << 2) + w;
        const float4* x4 = (const float4*)x;
        float4 v = x4[r * 96 + l];
        float s = v.x * v.x + v.y * v.y + v.z * v.z + v.w * v.w;
        if (l < 32) {
            float4 u = x4[r * 96 + 64 + l];
            s += u.x * u.x + u.y * u.y + u.z * u.z + u.w * u.w;
        }
        for (int off = 32; off; off >>= 1) s += __shfl_down(s, off);
        if (l == 0) { nx[r] = s; su[r] = -20.f * s; }
    } else {
        if (t == 0) { colerr[0] = 0u; colerr[1] = 0u; active[0] = 1; out[0] = 0.f; }
    }
}

// ---------------------------------------------------------------- gemm ------
// G[i,j] = 40 * dot(x_i, y_j).  64x64 block tile, 4x4 per thread, direct
// global loads (x/y frags are L1-resident broadcasts). fp32: one-time cost.
__global__ __launch_bounds__(256) void gemm_k(
    const float* __restrict__ x, const float* __restrict__ y, float* __restrict__ G)
{
    const int t  = threadIdx.x;
    const int tx = t & 15, ty = t >> 4;
    const int i0 = (blockIdx.y << 6) + (ty << 2);
    const int j0 = (blockIdx.x << 6) + (tx << 2);
    const float4* x4 = (const float4*)x;
    const float4* y4 = (const float4*)y;
    float acc[4][4];
#pragma unroll
    for (int a = 0; a < 4; ++a)
#pragma unroll
        for (int c = 0; c < 4; ++c) acc[a][c] = 0.f;

    for (int kq = 0; kq < 96; ++kq) {
        float4 av[4], bv[4];
#pragma unroll
        for (int a = 0; a < 4; ++a) av[a] = x4[(i0 + a) * 96 + kq];
#pragma unroll
        for (int c = 0; c < 4; ++c) bv[c] = y4[(j0 + c) * 96 + kq];
#pragma unroll
        for (int a = 0; a < 4; ++a)
#pragma unroll
            for (int c = 0; c < 4; ++c)
                acc[a][c] += av[a].x * bv[c].x + av[a].y * bv[c].y +
                             av[a].z * bv[c].z + av[a].w * bv[c].w;
    }
    float4* G4 = (float4*)G;
#pragma unroll
    for (int a = 0; a < 4; ++a) {
        float4 o = make_float4(40.f * acc[a][0], 40.f * acc[a][1],
                               40.f * acc[a][2], 40.f * acc[a][3]);
        G4[(i0 + a) * 8192 + (j0 >> 2)] = o;
    }
}

// ------------------------------------------------------------ iteration -----
// One fused Sinkhorn iteration pass. Block b owns columns [64b, 64b+64).
// Each thread caches a 16(row-strided) x 4(col) register tile of G.
__global__ __launch_bounds__(256) void sink_iter(
    const float* __restrict__ G, const float* __restrict__ su,
    float* __restrict__ W, float* __restrict__ pmT, float* __restrict__ psT,
    const int* __restrict__ active, int gated)
{
    if (gated && active[0] == 0) return;
    __shared__ float su_lds[256];
    __shared__ float comb[1024];
    __shared__ float Mlds[64];
    __shared__ float Wlds[64];
    __shared__ float m_arr[256 * 17];
    __shared__ float s_arr[256 * 17];

    const int t  = threadIdx.x;
    const int b  = blockIdx.x;
    const int j0 = b << 6;
    const int jq = t & 15;       // column quad 0..15 (4 cols each)
    const int is = t >> 4;       // row subset 0..15 (rows is+16k)

    su_lds[t] = su[t];
    __syncthreads();

    const float4* G4 = (const float4*)G;
    float4 tile[16];
    float  sur[16];
#pragma unroll
    for (int k = 0; k < 16; ++k) {
        int i = is + (k << 4);
        tile[k] = G4[i * 8192 + (j0 >> 2) + jq];
        sur[k]  = su_lds[i];
    }

    // ---- phase C: column logsumexp over i (exact two-pass from registers)
    float m0 = -INFINITY, m1 = -INFINITY, m2 = -INFINITY, m3 = -INFINITY;
#pragma unroll
    for (int k = 0; k < 16; ++k) {
        m0 = fmaxf(m0, tile[k].x + sur[k]);
        m1 = fmaxf(m1, tile[k].y + sur[k]);
        m2 = fmaxf(m2, tile[k].z + sur[k]);
        m3 = fmaxf(m3, tile[k].w + sur[k]);
    }
    ((float4*)comb)[(is << 4) + jq] = make_float4(m0, m1, m2, m3);
    __syncthreads();
    if (t < 64) {
        float m = -INFINITY;
#pragma unroll
        for (int s = 0; s < 16; ++s) m = fmaxf(m, comb[(s << 6) + t]);
        Mlds[t] = m;
    }
    __syncthreads();
    float4 Mq = make_float4(Mlds[4 * jq + 0], Mlds[4 * jq + 1],
                            Mlds[4 * jq + 2], Mlds[4 * jq + 3]);
    float s0 = 0.f, s1 = 0.f, s2 = 0.f, s3 = 0.f;
#pragma unroll
    for (int k = 0; k < 16; ++k) {
        s0 += __expf(tile[k].x + sur[k] - Mq.x);
        s1 += __expf(tile[k].y + sur[k] - Mq.y);
        s2 += __expf(tile[k].z + sur[k] - Mq.z);
        s3 += __expf(tile[k].w + sur[k] - Mq.w);
    }
    ((float4*)comb)[(is << 4) + jq] = make_float4(s0, s1, s2, s3);
    __syncthreads();
    if (t < 64) {
        float ssum = 0.f;
#pragma unroll
        for (int s = 0; s < 16; ++s) ssum += comb[(s << 6) + t];
        float Wj = LOG_B - (Mlds[t] + __logf(ssum));
        Wlds[t] = Wj;
        W[j0 + t] = Wj;
    }
    __syncthreads();
    float4 Wq = make_float4(Wlds[4 * jq + 0], Wlds[4 * jq + 1],
                            Wlds[4 * jq + 2], Wlds[4 * jq + 3]);

    // ---- phase R: per-row partial lse over this block's 64 columns
#pragma unroll
    for (int k = 0; k < 16; ++k) {
        float a0 = tile[k].x + Wq.x;
        float a1 = tile[k].y + Wq.y;
        float a2 = tile[k].z + Wq.z;
        float a3 = tile[k].w + Wq.w;
        float m = fmaxf(fmaxf(a0, a1), fmaxf(a2, a3));
        float s = __expf(a0 - m) + __expf(a1 - m) + __expf(a2 - m) + __expf(a3 - m);
        int i = is + (k << 4);
        m_arr[i * 17 + jq] = m;   // stride 17: ~2-way banks only
        s_arr[i * 17 + jq] = s;
    }
    __syncthreads();
    {   // thread t combines the 16 column-quad partials of row t
        float m = -INFINITY, s = 0.f;
#pragma unroll
        for (int p = 0; p < 16; ++p) {
            float pm = m_arr[t * 17 + p];
            float ps = s_arr[t * 17 + p];
            float nm = fmaxf(m, pm);
            s = s * __expf(m - nm) + ps * __expf(pm - nm);
            m = nm;
        }
        pmT[(t << 9) + b] = m;    // [row][block] layout -> coalesced combine
        psT[(t << 9) + b] = s;
    }
}

// ------------------------------------------------- row-partial combine ------
// block i: exact lse-combine of 512 block partials -> su'[i] = log_a - L2[i]
__global__ __launch_bounds__(64) void sink_combine(
    const float* __restrict__ pmT, const float* __restrict__ psT,
    float* __restrict__ su, const int* __restrict__ active, int gated)
{
    if (gated && active[0] == 0) return;
    const int i = blockIdx.x, p = threadIdx.x;
    float m = -INFINITY, s = 0.f;
#pragma unroll
    for (int q = 0; q < 8; ++q) {
        float pm = pmT[(i << 9) + p + (q << 6)];
        float ps = psT[(i << 9) + p + (q << 6)];
        float nm = fmaxf(m, pm);
        s = s * __expf(m - nm) + ps * __expf(pm - nm);
        m = nm;
    }
    for (int off = 32; off; off >>= 1) {
        float om = __shfl_down(m, off);
        float os = __shfl_down(s, off);
        float nm = fmaxf(m, om);
        s = s * __expf(m - nm) + os * __expf(om - nm);
        m = nm;
    }
    if (p == 0) su[i] = LOG_A - (m + __logf(s));
}

// --------------------------------------------- absorb-step column error -----
// col[j] = exp(lse_i(G+su') + W[j]);  err_col = max_j |col - b|.
// (Row marginal is exactly 'a' after the u-update -> only columns matter.)
__global__ __launch_bounds__(256) void sink_colerr(
    const float* __restrict__ G, const float* __restrict__ su,
    const float* __restrict__ W, unsigned* __restrict__ colerr, int slot,
    const int* __restrict__ active, int gated)
{
    if (gated && active[0] == 0) return;
    __shared__ float su_lds[256];
    __shared__ float comb[1024];
    __shared__ float Mlds[64];

    const int t  = threadIdx.x;
    const int b  = blockIdx.x;
    const int j0 = b << 6;
    const int jq = t & 15;
    const int is = t >> 4;

    su_lds[t] = su[t];
    __syncthreads();

    const float4* G4 = (const float4*)G;
    float4 tile[16];
    float  sur[16];
#pragma unroll
    for (int k = 0; k < 16; ++k) {
        int i = is + (k << 4);
        tile[k] = G4[i * 8192 + (j0 >> 2) + jq];
        sur[k]  = su_lds[i];
    }
    float m0 = -INFINITY, m1 = -INFINITY, m2 = -INFINITY, m3 = -INFINITY;
#pragma unroll
    for (int k = 0; k < 16; ++k) {
        m0 = fmaxf(m0, tile[k].x + sur[k]);
        m1 = fmaxf(m1, tile[k].y + sur[k]);
        m2 = fmaxf(m2, tile[k].z + sur[k]);
        m3 = fmaxf(m3, tile[k].w + sur[k]);
    }
    ((float4*)comb)[(is << 4) + jq] = make_float4(m0, m1, m2, m3);
    __syncthreads();
    if (t < 64) {
        float m = -INFINITY;
#pragma unroll
        for (int s = 0; s < 16; ++s) m = fmaxf(m, comb[(s << 6) + t]);
        Mlds[t] = m;
    }
    __syncthreads();
    float4 Mq = make_float4(Mlds[4 * jq + 0], Mlds[4 * jq + 1],
                            Mlds[4 * jq + 2], Mlds[4 * jq + 3]);
    float s0 = 0.f, s1 = 0.f, s2 = 0.f, s3 = 0.f;
#pragma unroll
    for (int k = 0; k < 16; ++k) {
        s0 += __expf(tile[k].x + sur[k] - Mq.x);
        s1 += __expf(tile[k].y + sur[k] - Mq.y);
        s2 += __expf(tile[k].z + sur[k] - Mq.z);
        s3 += __expf(tile[k].w + sur[k] - Mq.w);
    }
    ((float4*)comb)[(is << 4) + jq] = make_float4(s0, s1, s2, s3);
    __syncthreads();
    if (t < 64) {
        float ssum = 0.f;
#pragma unroll
        for (int s = 0; s < 16; ++s) ssum += comb[(s << 6) + t];
        float Aj  = Mlds[t] + __logf(ssum);
        float col = __expf(Aj + W[j0 + t]);
        float d   = fabsf(col - BVAL);
        for (int off = 32; off; off >>= 1) d = fmaxf(d, __shfl_down(d, off));
        if (t == 0) atomicMax(colerr + slot, __float_as_uint(d));  // d >= 0
    }
}

__global__ void sink_check(const unsigned* __restrict__ colerr, int slot,
                           int* __restrict__ active)
{
    if (threadIdx.x == 0)
        active[0] = (__uint_as_float(colerr[slot]) > 0.005f) ? 1 : 0;
}

// ------------------------------------------------------------- finalize -----
__global__ __launch_bounds__(256) void finalize_k(
    const float* __restrict__ G, const float* __restrict__ su,
    const float* __restrict__ W, const float* __restrict__ nx,
    const float* __restrict__ ny, float* __restrict__ out)
{
    __shared__ float su_lds[256], nx_lds[256];
    __shared__ float red[4];
    const int t = threadIdx.x, b = blockIdx.x;
    const int j0 = b << 6;
    su_lds[t] = su[t];
    nx_lds[t] = nx[t];
    __syncthreads();
    const int jj = t & 63, ig = t >> 6;
    const int j = j0 + jj;
    const float Wj = W[j], nyj = ny[j];
    float acc = 0.f;
#pragma unroll 4
    for (int k = 0; k < 64; ++k) {
        int i = ig + (k << 2);
        float g = G[i * 32768 + j];
        float v = __expf(g + su_lds[i] + Wj);
        out[1 + (size_t)i * 32768 + j] = v;
        acc += v * (nx_lds[i] + nyj - 0.05f * g);
    }
    for (int off = 32; off; off >>= 1) acc += __shfl_down(acc, off);
    if ((t & 63) == 0) red[t >> 6] = acc;
    __syncthreads();
    if (t == 0) atomicAdd(out, red[0] + red[1] + red[2] + red[3]);
}

// ---------------------------------------------------------------- host ------
extern "C" void kernel_launch(void* const* d_in, const int* in_sizes, int n_in,
                              void* d_out, int out_size, void* d_ws, size_t ws_size,
                              hipStream_t stream)
{
    const float* x = (const float*)d_in[0];   // [256, 384]
    const float* y = (const float*)d_in[1];   // [32768, 384]
    float* out = (float*)d_out;               // [1 + 256*32768]

    float* ws   = (float*)d_ws;
    float* G    = ws;                 // 8388608
    float* Wv   = G + 8388608;        // 32768
    float* su   = Wv + 32768;         // 256
    float* nx   = su + 256;           // 256
    float* ny   = nx + 256;           // 32768
    float* pmT  = ny + 32768;         // 131072  [row][block]
    float* psT  = pmT + 131072;       // 131072
    unsigned* colerr = (unsigned*)(psT + 131072);  // 2
    int* active = (int*)(colerr + 2);              // 1

    init_k<<<8257, 256, 0, stream>>>(x, y, nx, ny, su, colerr, active, out);
    gemm_k<<<dim3(512, 4), 256, 0, stream>>>(x, y, G);

    // iteration 1 (always runs) + absorb error check
    sink_iter<<<512, 256, 0, stream>>>(G, su, Wv, pmT, psT, active, 0);
    sink_combine<<<256, 64, 0, stream>>>(pmT, psT, su, active, 0);
    sink_colerr<<<512, 256, 0, stream>>>(G, su, Wv, colerr, 0, active, 0);
    sink_check<<<1, 64, 0, stream>>>(colerr, 0, active);

    for (int tt = 2; tt <= 100; ++tt) {
        sink_iter<<<512, 256, 0, stream>>>(G, su, Wv, pmT, psT, active, 1);
        sink_combine<<<256, 64, 0, stream>>>(pmT, psT, su, active, 1);
        if (tt == 51) {   // absorb at cpt_n=51: error check gates the rest
            sink_colerr<<<512, 256, 0, stream>>>(G, su, Wv, colerr, 1, active, 1);
            sink_check<<<1, 64, 0, stream>>>(colerr, 1, active);
        }
    }

    finalize_k<<<512, 256, 0, stream>>>(G, su, Wv, nx, ny, out);
}